// Round 16
// baseline (558.903 us; speedup 1.0000x reference)
//
#include <hip/hip_runtime.h>
#include <hip/hip_bf16.h>

#define NN 50000
#define EE 800000
#define GG 16
#define IN_DIM 256
#define HID 64
#define NEG 0.2f
#define SCAN_NB 49   // ceil(50000/1024)
#define SMT 40       // nodes per matmul block (50000 = 1250*40)
#define PROJ_B (NN / SMT)   // 1250
#define ATT_B (NN / 4)      // 12500
#define EDGE_B (EE / 256)   // 3125
#define SEL_B ((NN + 255) / 256) // 196

__device__ inline float wred_sum(float v) {
    for (int o = 32; o > 0; o >>= 1) v += __shfl_xor(v, o, 64);
    return v;
}
__device__ inline float wred_max(float v) {
    for (int o = 32; o > 0; o >>= 1) v = fmaxf(v, __shfl_xor(v, o, 64));
    return v;
}
// sum float4 across the 4 slot groups (lanes differing in bits 4,5)
__device__ inline void slot_reduce4(float4& a) {
    a.x += __shfl_xor(a.x, 16, 64); a.y += __shfl_xor(a.y, 16, 64);
    a.z += __shfl_xor(a.z, 16, 64); a.w += __shfl_xor(a.w, 16, 64);
    a.x += __shfl_xor(a.x, 32, 64); a.y += __shfl_xor(a.y, 32, 64);
    a.z += __shfl_xor(a.z, 32, 64); a.w += __shfl_xor(a.w, 32, 64);
}

__device__ inline float lrelu(float a) { return a > 0.f ? a : NEG * a; }

// ---- scan stage 1: per-block exclusive scan of deg, block totals ----
__global__ __launch_bounds__(1024) void scan1_kernel(const int* __restrict__ deg,
                                                     int* __restrict__ row_off,
                                                     int* __restrict__ bsum) {
    __shared__ int buf[1024];
    int b = blockIdx.x;
    int i = b * 1024 + threadIdx.x;
    int v = (i < NN) ? deg[i] : 0;
    buf[threadIdx.x] = v;
    __syncthreads();
    for (int ofs = 1; ofs < 1024; ofs <<= 1) {
        int t = (threadIdx.x >= ofs) ? buf[threadIdx.x - ofs] : 0;
        __syncthreads();
        buf[threadIdx.x] += t;
        __syncthreads();
    }
    if (i < NN) row_off[i] = buf[threadIdx.x] - v;   // local exclusive
    if (threadIdx.x == 1023) bsum[b] = buf[1023];
}

// ---- scan stage 2: single-wave scan of block totals ----
__global__ __launch_bounds__(64) void scan2_kernel(const int* __restrict__ bsum,
                                                   int* __restrict__ boff,
                                                   int* __restrict__ row_off) {
    int l = threadIdx.x;
    int v = (l < SCAN_NB) ? bsum[l] : 0;
    int incl = v;
    for (int ofs = 1; ofs < 64; ofs <<= 1) {
        int t = __shfl_up(incl, ofs, 64);
        if (l >= ofs) incl += t;
    }
    if (l < SCAN_NB) boff[l] = incl - v;
    if (l == 63) row_off[NN] = incl;
}

// ---- scan stage 3: apply block offsets, derive pos/inv_deg ----
__global__ __launch_bounds__(1024) void scan3_kernel(const int* __restrict__ deg,
                                                     const int* __restrict__ boff,
                                                     int* __restrict__ row_off,
                                                     int* __restrict__ pos,
                                                     float* __restrict__ inv_deg) {
    int b = blockIdx.x;
    int i = b * 1024 + threadIdx.x;
    if (i >= NN) return;
    int ro = row_off[i] + boff[b];
    row_off[i] = ro;
    pos[i] = ro;
    float idg = 1.0f / fmaxf((float)deg[i], 1.0f);
    inv_deg[i] = idg;
}

// ---- ALL weight prep in one dispatch ----
__global__ __launch_bounds__(128) void weights_kernel(const float* __restrict__ wl,
                                                      const float* __restrict__ wr,
                                                      float* __restrict__ wtp,
                                                      const float* __restrict__ w0,
                                                      const float* __restrict__ as0,
                                                      const float* __restrict__ ad0,
                                                      const float* __restrict__ we0,
                                                      const float* __restrict__ ae0,
                                                      const float* __restrict__ w1,
                                                      const float* __restrict__ as1,
                                                      const float* __restrict__ ad1,
                                                      const float* __restrict__ we1,
                                                      const float* __restrict__ ae1,
                                                      const float* __restrict__ w2,
                                                      const float* __restrict__ as2,
                                                      const float* __restrict__ ad2,
                                                      const float* __restrict__ we2,
                                                      const float* __restrict__ ae2,
                                                      float* __restrict__ wtg3,
                                                      float* __restrict__ asw3,
                                                      float* __restrict__ adw3,
                                                      float* __restrict__ wedot3) {
    int b = blockIdx.x;
    int j = threadIdx.x;     // 0..127
    if (b < 256) {
        int k = b;
        float v = (j < 64) ? wl[j * 256 + k] : wr[(j - 64) * 256 + k];
        wtp[(k >> 2) * 512 + j * 4 + (k & 3)] = v;
        return;
    }
    int L = (b - 256) >> 6;
    int k = (b - 256) & 63;
    const float* w  = (L == 0) ? w0  : (L == 1) ? w1  : w2;
    const float* as = (L == 0) ? as0 : (L == 1) ? as1 : as2;
    const float* ad = (L == 0) ? ad0 : (L == 1) ? ad1 : ad2;
    const float* we = (L == 0) ? we0 : (L == 1) ? we1 : we2;
    const float* ae = (L == 0) ? ae0 : (L == 1) ? ae1 : ae2;
    int H64 = (L == 2) ? 64 : 128;
    if (j >= H64) return;
    int h = j >> 6;
    int c = j & 63;
    float wv = w[j * 64 + k];
    wtg3[L * 8192 + (k >> 2) * (H64 * 4) + j * 4 + (k & 3)] = wv;
    float sv = wred_sum(wv * as[j]);
    float dv = wred_sum(wv * ad[j]);
    if (c == 0) {
        asw3[L * 128 + h * 64 + k] = sv;
        adw3[L * 128 + h * 64 + k] = dv;
    }
    if (k == 0) {
        float wd = wred_sum(we[j] * ae[j]);
        if (c == 0) wedot3[L * 2 + h] = wd;
    }
}

// ---- FUSED: sage_mm (blocks 0..1249; SMT=40, 20KB LDS, 2-stage K — fmaf chain
//      verbatim) + deg count (blocks 1250..4374) + pool-node sel (4375..).
//      sage doesn't depend on the scans, so it runs a stage earlier now,
//      overlapped with the atomic-latency-bound degree count. ----
__global__ __launch_bounds__(256) void sage_deg_sel_kernel(const float* __restrict__ x,
                                                           const float* __restrict__ wtp,
                                                           float* __restrict__ xl,
                                                           float* __restrict__ xr,
                                                           const int* __restrict__ ei,
                                                           int* __restrict__ deg,
                                                           const int* __restrict__ ntype,
                                                           int* __restrict__ nodesel,
                                                           int* __restrict__ nsel) {
    __shared__ float xs[SMT * 128];          // 20 KB: one K-half of the 40-node tile
    if (blockIdx.x >= PROJ_B) {
        int b = blockIdx.x - PROJ_B;
        if (b < EDGE_B) {
            int e = b * 256 + threadIdx.x;
            if (e >= EE) return;
            int d = ei[EE + e];
            atomicAdd(&deg[d], 1);
            return;
        }
        int n = (b - EDGE_B) * 256 + threadIdx.x;
        if (n >= NN) return;
        int t = ntype[n];
        if (t == 1 || t == 2) {
            int p = atomicAdd(nsel, 1);
            nodesel[p] = n;
        }
        return;
    }
    int node0 = blockIdx.x * SMT;
    const float4* x4 = (const float4*)(x + (size_t)node0 * 256);
    float4* xs4 = (float4*)xs;
    int jj = threadIdx.x & 63;
    int g = threadIdx.x >> 6;           // node group: 10 nodes each
    float accL[10], accR[10];
#pragma unroll
    for (int n = 0; n < 10; n++) { accL[n] = 0.f; accR[n] = 0.f; }
    for (int stage = 0; stage < 2; ++stage) {
        __syncthreads();                 // previous half's compute done before overwrite
        for (int t = threadIdx.x; t < SMT * 32; t += 256) {
            int node = t >> 5;
            int kk = t & 31;
            xs4[t] = x4[node * 64 + stage * 32 + kk];
        }
        __syncthreads();
        for (int k4i = 0; k4i < 32; k4i++) {
            int k4 = stage * 32 + k4i;
            const float4 wL = *(const float4*)&wtp[k4 * 512 + jj * 4];
            const float4 wR = *(const float4*)&wtp[k4 * 512 + (jj + 64) * 4];
#pragma unroll
            for (int n = 0; n < 10; n++) {
                const float4 xv = xs4[(g * 10 + n) * 32 + k4i];
                accL[n] = fmaf(xv.x, wL.x, accL[n]);
                accL[n] = fmaf(xv.y, wL.y, accL[n]);
                accL[n] = fmaf(xv.z, wL.z, accL[n]);
                accL[n] = fmaf(xv.w, wL.w, accL[n]);
                accR[n] = fmaf(xv.x, wR.x, accR[n]);
                accR[n] = fmaf(xv.y, wR.y, accR[n]);
                accR[n] = fmaf(xv.z, wR.z, accR[n]);
                accR[n] = fmaf(xv.w, wR.w, accR[n]);
            }
        }
    }
#pragma unroll
    for (int n = 0; n < 10; n++) {
        int node = node0 + g * 10 + n;
        xl[(size_t)node * 64 + jj] = accL[n];
        xr[(size_t)node * 64 + jj] = accR[n];
    }
}

// ---- standalone CSR fill (packed int2: one cacheline per edge) ----
__global__ __launch_bounds__(256) void fill_kernel(const int* __restrict__ ei,
                                                   const float* __restrict__ eattr,
                                                   int* __restrict__ pos,
                                                   int2* __restrict__ csr_pk) {
    int e = blockIdx.x * 256 + threadIdx.x;
    if (e >= EE) return;
    int d = ei[EE + e];
    int p = atomicAdd(&pos[d], 1);
    csr_pk[p] = make_int2(ei[e], __float_as_int(eattr[e]));
}

// ---- FUSED: proj_mm<H> (blocks 0..1249) + attval (blocks 1250..) ----
template <int H>
__global__ __launch_bounds__(256) void proj_attval_kernel(const float* __restrict__ hin,
                                                          const float* __restrict__ wtgp,
                                                          float* __restrict__ hproj,
                                                          const float* __restrict__ asw,
                                                          const float* __restrict__ adw,
                                                          float* __restrict__ sval,
                                                          float* __restrict__ dval) {
    __shared__ float xs[SMT * 64];
    if (blockIdx.x < PROJ_B) {
        int node0 = blockIdx.x * SMT;
        const float4* h4 = (const float4*)(hin + (size_t)node0 * 64);
        float4* xs4 = (float4*)xs;
        for (int t = threadIdx.x; t < SMT * 16; t += 256) xs4[t] = h4[t];
        __syncthreads();
        int jj = threadIdx.x & 63;
        int g = threadIdx.x >> 6;
        float acc[H][10];
#pragma unroll
        for (int h = 0; h < H; h++)
#pragma unroll
            for (int n = 0; n < 10; n++) acc[h][n] = 0.f;
#pragma unroll 4
        for (int k4 = 0; k4 < 16; k4++) {
            float4 wv[H];
#pragma unroll
            for (int h = 0; h < H; h++)
                wv[h] = *(const float4*)&wtgp[k4 * (H * 256) + (h * 64 + jj) * 4];
#pragma unroll
            for (int n = 0; n < 10; n++) {
                const float4 xv = xs4[(g * 10 + n) * 16 + k4];
#pragma unroll
                for (int h = 0; h < H; h++) {
                    acc[h][n] = fmaf(xv.x, wv[h].x, acc[h][n]);
                    acc[h][n] = fmaf(xv.y, wv[h].y, acc[h][n]);
                    acc[h][n] = fmaf(xv.z, wv[h].z, acc[h][n]);
                    acc[h][n] = fmaf(xv.w, wv[h].w, acc[h][n]);
                }
            }
        }
#pragma unroll
        for (int h = 0; h < H; h++)
#pragma unroll
            for (int n = 0; n < 10; n++)
                hproj[(size_t)(node0 + g * 10 + n) * (H * 64) + h * 64 + jj] = acc[h][n];
        return;
    }
    // attval body (verbatim)
    int wid = ((blockIdx.x - PROJ_B) * 256 + threadIdx.x) >> 6;
    int lane = threadIdx.x & 63;
    if (wid >= NN) return;
    float hv = hin[(size_t)wid * 64 + lane];
    for (int h = 0; h < H; ++h) {
        float sv = wred_sum(hv * asw[h * 64 + lane]);
        float dv = wred_sum(hv * adw[h * 64 + lane]);
        if (lane == 0) {
            sval[wid * H + h] = sv;
            dval[wid * H + h] = dv;
        }
    }
}

// ---- SAGE aggregation + combine + relu; also computes mean_e from the CSR bucket ----
__global__ __launch_bounds__(256) void sage_agg_kernel(const float* __restrict__ xl,
                                                       const float* __restrict__ xr,
                                                       const float* __restrict__ bl,
                                                       const float* __restrict__ inv_deg,
                                                       const int* __restrict__ row_off,
                                                       const int2* __restrict__ csr_pk,
                                                       float* __restrict__ hout,
                                                       float* __restrict__ mean_e) {
    int wid = blockIdx.x * 4 + (threadIdx.x >> 6);
    int lane = threadIdx.x & 63;
    if (wid >= NN) return;
    int slot = lane >> 4;
    int c4 = lane & 15;
    int r0 = row_off[wid], r1 = row_off[wid + 1];
    float4 acc = make_float4(0.f, 0.f, 0.f, 0.f);
    float es = 0.f;
    // unroll duplicates the body; fma/add chain order per lane is unchanged
#pragma unroll 4
    for (int idx = r0 + slot; idx < r1; idx += 4) {
        int2 cp = csr_pk[idx];
        int s = cp.x;
        es += __int_as_float(cp.y);
        const float4 hp = *(const float4*)&xl[(size_t)s * 64 + c4 * 4];
        acc.x += hp.x; acc.y += hp.y; acc.z += hp.z; acc.w += hp.w;
    }
    slot_reduce4(acc);
    es += __shfl_xor(es, 16, 64);   // lanes within a slot hold identical es
    es += __shfl_xor(es, 32, 64);   // -> every lane now has the bucket sum
    if (slot == 0) {
        float idg = inv_deg[wid];
        if (c4 == 0) mean_e[wid] = es * idg;
        const float4 b4 = *(const float4*)&bl[c4 * 4];
        const float4 xr4 = *(const float4*)&xr[(size_t)wid * 64 + c4 * 4];
        float4 v;
        v.x = fmaxf(acc.x * idg + b4.x + xr4.x, 0.f);
        v.y = fmaxf(acc.y * idg + b4.y + xr4.y, 0.f);
        v.z = fmaxf(acc.z * idg + b4.z + xr4.z, 0.f);
        v.w = fmaxf(acc.w * idg + b4.w + xr4.w, 0.f);
        *(float4*)&hout[(size_t)wid * 64 + c4 * 4] = v;
    }
}

// ---- GAT: frozen FP bodies (round-5 expressions verbatim); packed int2 loads. ----
__global__ __launch_bounds__(256) void gat_kernel(const float* __restrict__ hproj,
                                                  const float* __restrict__ sval,
                                                  const float* __restrict__ dval,
                                                  const float* __restrict__ wedot_buf,
                                                  const float* __restrict__ bias,
                                                  const float* __restrict__ mean_e,
                                                  const int* __restrict__ row_off,
                                                  const int2* __restrict__ csr_pk,
                                                  float* __restrict__ hout, int H,
                                                  const int* __restrict__ nodesel,
                                                  const int* __restrict__ nsel) {
    int wid = blockIdx.x * 4 + (threadIdx.x >> 6);
    int lane = threadIdx.x & 63;
    if (nodesel) {
        if (wid >= *nsel) return;
        wid = nodesel[wid];
    }
    if (wid >= NN) return;
    int slot = lane >> 4;
    int c4 = lane & 15;
    int H64 = H * 64;
    int r0 = row_off[wid], r1 = row_off[wid + 1];
    float me = mean_e[wid];
    float4 acc = make_float4(0.f, 0.f, 0.f, 0.f);
    for (int h = 0; h < H; ++h) {
        float wedot = wedot_buf[h];
        float dv = dval[wid * H + h];
        float a_self = lrelu(sval[wid * H + h] + dv + me * wedot);
        // single pass: online max + denom, lane-strided
        float m_l = -INFINITY, den_l = 0.f;
        for (int idx = r0 + lane; idx < r1; idx += 64) {
            int2 cp = csr_pk[idx];
            int s = cp.x;
            float a = lrelu(sval[s * H + h] + dv + __int_as_float(cp.y) * wedot);
            float mn = fmaxf(m_l, a);
            den_l = den_l * __expf(m_l - mn) + __expf(a - mn);
            m_l = mn;
        }
        float m = fmaxf(wred_max(m_l), a_self);
        float den = wred_sum(den_l * __expf(m_l - m)) + __expf(a_self - m);
        float inv_den = 1.0f / den;
        // weighted gather: 4 edges in flight (one per slot), float4 per lane
        for (int idx = r0 + slot; idx < r1; idx += 4) {
            int2 cp = csr_pk[idx];
            int s = cp.x;
            float a = lrelu(sval[s * H + h] + dv + __int_as_float(cp.y) * wedot);
            float c = __expf(a - m) * inv_den;
            const float4 hp = *(const float4*)&hproj[(size_t)s * H64 + h * 64 + c4 * 4];
            acc.x = fmaf(c, hp.x, acc.x);
            acc.y = fmaf(c, hp.y, acc.y);
            acc.z = fmaf(c, hp.z, acc.z);
            acc.w = fmaf(c, hp.w, acc.w);
        }
        if (slot == 0) {  // self-loop contribution
            float c = __expf(a_self - m) * inv_den;
            const float4 hp = *(const float4*)&hproj[(size_t)wid * H64 + h * 64 + c4 * 4];
            acc.x = fmaf(c, hp.x, acc.x);
            acc.y = fmaf(c, hp.y, acc.y);
            acc.z = fmaf(c, hp.z, acc.z);
            acc.w = fmaf(c, hp.w, acc.w);
        }
    }
    slot_reduce4(acc);
    if (slot == 0) {
        float invH = 1.0f / (float)H;
        const float4 b4 = *(const float4*)&bias[c4 * 4];
        float4 v;
        v.x = fmaxf(acc.x * invH + b4.x, 0.f);
        v.y = fmaxf(acc.y * invH + b4.y, 0.f);
        v.z = fmaxf(acc.z * invH + b4.z, 0.f);
        v.w = fmaxf(acc.w * invH + b4.w, 0.f);
        *(float4*)&hout[(size_t)wid * 64 + c4 * 4] = v;
    }
}

// ---- masked mean pool: batch sorted -> register accumulate, flush on boundary ----
__global__ __launch_bounds__(256) void pool_kernel(const float* __restrict__ h,
                                                   const int* __restrict__ ntype,
                                                   const int* __restrict__ batch,
                                                   float* __restrict__ pool,
                                                   float* __restrict__ cnt) {
    int nwaves = gridDim.x * 4;
    int wid = blockIdx.x * 4 + (threadIdx.x >> 6);
    int lane = threadIdx.x & 63;
    int chunk = (NN + nwaves - 1) / nwaves;
    int n0 = wid * chunk;
    int n1 = min(n0 + chunk, NN);
    if (n0 >= NN) return;
    float acc1 = 0.f, acc2 = 0.f;
    int c1 = 0, c2 = 0;
    int cur_g = batch[n0];
    for (int n = n0; n < n1; ++n) {
        int g = batch[n];
        if (g != cur_g) {
            if (c1) {
                atomicAdd(&pool[(0 * GG + cur_g) * 64 + lane], acc1);
                if (lane == 0) atomicAdd(&cnt[0 * GG + cur_g], (float)c1);
            }
            if (c2) {
                atomicAdd(&pool[(1 * GG + cur_g) * 64 + lane], acc2);
                if (lane == 0) atomicAdd(&cnt[1 * GG + cur_g], (float)c2);
            }
            acc1 = acc2 = 0.f;
            c1 = c2 = 0;
            cur_g = g;
        }
        int t = ntype[n];
        if (t == 1) { acc1 += h[n * 64 + lane]; c1++; }
        else if (t == 2) { acc2 += h[n * 64 + lane]; c2++; }
    }
    if (c1) {
        atomicAdd(&pool[(0 * GG + cur_g) * 64 + lane], acc1);
        if (lane == 0) atomicAdd(&cnt[0 * GG + cur_g], (float)c1);
    }
    if (c2) {
        atomicAdd(&pool[(1 * GG + cur_g) * 64 + lane], acc2);
        if (lane == 0) atomicAdd(&cnt[1 * GG + cur_g], (float)c2);
    }
}

// ---- final MLP ----
__global__ __launch_bounds__(256) void mlp_kernel(const float* __restrict__ pool,
                                                  const float* __restrict__ cnt,
                                                  const float* __restrict__ w1,
                                                  const float* __restrict__ b1,
                                                  const float* __restrict__ w2,
                                                  const float* __restrict__ b2,
                                                  float* __restrict__ out) {
    __shared__ float ro[GG * 128];
    __shared__ float hid[GG * 64];
    int tid = threadIdx.x;
    for (int t = tid; t < GG * 128; t += 256) {
        int g = t >> 7;
        int j = t & 127;
        int part = j >> 6;
        float c = fmaxf(cnt[part * GG + g], 1.0f);
        ro[t] = pool[(part * GG + g) * 64 + (j & 63)] / c;
    }
    __syncthreads();
    for (int t = tid; t < GG * 64; t += 256) {
        int g = t >> 6;
        int i = t & 63;
        float s = b1[i];
        for (int j = 0; j < 128; j++) s = fmaf(ro[g * 128 + j], w1[i * 128 + j], s);
        hid[t] = fmaxf(s, 0.f);
    }
    __syncthreads();
    if (tid < GG) {
        float s = b2[0];
        for (int i = 0; i < 64; i++) s = fmaf(hid[tid * 64 + i], w2[i], s);
        out[tid] = s;
    }
}

extern "C" void kernel_launch(void* const* d_in, const int* in_sizes, int n_in,
                              void* d_out, int out_size, void* d_ws, size_t ws_size,
                              hipStream_t stream) {
    const float* x       = (const float*)d_in[0];
    const int*   ei      = (const int*)d_in[1];
    const int*   ntype   = (const int*)d_in[2];
    const float* eattr   = (const float*)d_in[3];
    const int*   batch   = (const int*)d_in[4];
    const float* sage_wl = (const float*)d_in[5];
    const float* sage_bl = (const float*)d_in[6];
    const float* sage_wr = (const float*)d_in[7];
    const float* mlp_w1  = (const float*)d_in[8];
    const float* mlp_b1  = (const float*)d_in[9];
    const float* mlp_w2  = (const float*)d_in[10];
    const float* mlp_b2  = (const float*)d_in[11];
    const float* gw[3]  = {(const float*)d_in[12], (const float*)d_in[18], (const float*)d_in[24]};
    const float* gas[3] = {(const float*)d_in[13], (const float*)d_in[19], (const float*)d_in[25]};
    const float* gad[3] = {(const float*)d_in[14], (const float*)d_in[20], (const float*)d_in[26]};
    const float* gwe[3] = {(const float*)d_in[15], (const float*)d_in[21], (const float*)d_in[27]};
    const float* gae[3] = {(const float*)d_in[16], (const float*)d_in[22], (const float*)d_in[28]};
    const float* gb[3]  = {(const float*)d_in[17], (const float*)d_in[23], (const float*)d_in[29]};

    char* base = (char*)d_ws;
    size_t o = 0;
    auto alloc = [&](size_t bytes) -> char* {
        char* p = base + o;
        o = (o + bytes + 255) & ~(size_t)255;
        return p;
    };
    // deg + nsel contiguous -> single memset
    char*  zblock1 = alloc(((size_t)NN + 1) * 4);
    int*   deg     = (int*)zblock1;
    int*   nsel    = (int*)(zblock1 + (size_t)NN * 4);
    float* mean_e  = (float*)alloc(NN * 4);
    float* inv_deg = (float*)alloc(NN * 4);
    int*   row_off = (int*)  alloc((NN + 1) * 4);
    int*   pos     = (int*)  alloc(NN * 4);
    int*   bsum    = (int*)  alloc(64 * 4);
    int*   boff    = (int*)  alloc(64 * 4);
    int*   nodesel = (int*)  alloc(NN * 4);
    int2*  csr_pk  = (int2*) alloc((size_t)EE * 8);
    float* xl      = (float*)alloc((size_t)NN * 64 * 4);
    float* xr      = (float*)alloc((size_t)NN * 64 * 4);
    float* hA      = (float*)alloc((size_t)NN * 64 * 4);
    float* hB      = (float*)alloc((size_t)NN * 64 * 4);
    float* hproj   = (float*)alloc((size_t)NN * 128 * 4);
    float* sval    = (float*)alloc((size_t)NN * 2 * 4);
    float* dval    = (float*)alloc((size_t)NN * 2 * 4);
    float* wt      = (float*)alloc(256 * 128 * 4);
    float* wtg3    = (float*)alloc(3 * 8192 * 4);
    float* asw3    = (float*)alloc(3 * 128 * 4);
    float* adw3    = (float*)alloc(3 * 128 * 4);
    float* wedot3  = (float*)alloc(3 * 2 * 4);
    // pools + cnt contiguous -> single memset
    char*  zblock2 = alloc((2 * GG * 64 + 2 * GG) * 4);
    float* pools   = (float*)zblock2;
    float* cnt     = (float*)(zblock2 + 2 * GG * 64 * 4);

    hipMemsetAsync(zblock1, 0, ((size_t)NN + 1) * 4, stream);
    hipMemsetAsync(zblock2, 0, (2 * GG * 64 + 2 * GG) * 4, stream);

    weights_kernel<<<448, 128, 0, stream>>>(sage_wl, sage_wr, wt,
                                            gw[0], gas[0], gad[0], gwe[0], gae[0],
                                            gw[1], gas[1], gad[1], gwe[1], gae[1],
                                            gw[2], gas[2], gad[2], gwe[2], gae[2],
                                            wtg3, asw3, adw3, wedot3);
    // sage GEMM (needs only wt) runs NOW, overlapped with degree count + selection
    sage_deg_sel_kernel<<<PROJ_B + EDGE_B + SEL_B, 256, 0, stream>>>(
        x, wt, xl, xr, ei, deg, ntype, nodesel, nsel);
    scan1_kernel<<<SCAN_NB, 1024, 0, stream>>>(deg, row_off, bsum);
    scan2_kernel<<<1, 64, 0, stream>>>(bsum, boff, row_off);
    scan3_kernel<<<SCAN_NB, 1024, 0, stream>>>(deg, boff, row_off, pos, inv_deg);
    fill_kernel<<<EDGE_B, 256, 0, stream>>>(ei, eattr, pos, csr_pk);

    sage_agg_kernel<<<NN / 4, 256, 0, stream>>>(xl, xr, sage_bl, inv_deg, row_off,
                                                csr_pk, hA, mean_e);

    float* hin = hA;
    float* hout = hB;
    for (int L = 0; L < 3; ++L) {
        int H = (L == 2) ? 1 : 2;
        const float* wtgL = wtg3 + (size_t)L * 8192;
        const float* aswL = asw3 + L * 128;
        const float* adwL = adw3 + L * 128;
        const float* wedL = wedot3 + L * 2;
        if (H == 2)
            proj_attval_kernel<2><<<PROJ_B + ATT_B, 256, 0, stream>>>(hin, wtgL, hproj,
                                                                     aswL, adwL, sval, dval);
        else
            proj_attval_kernel<1><<<PROJ_B + ATT_B, 256, 0, stream>>>(hin, wtgL, hproj,
                                                                     aswL, adwL, sval, dval);
        gat_kernel<<<NN / 4, 256, 0, stream>>>(hproj, sval, dval, wedL, gb[L],
                                               mean_e, row_off, csr_pk, hout, H,
                                               (L == 2) ? nodesel : nullptr,
                                               (L == 2) ? nsel : nullptr);
        float* tmp = hin; hin = hout; hout = tmp;
    }
    // final features now in hin
    pool_kernel<<<1024, 256, 0, stream>>>(hin, ntype, batch, pools, cnt);
    mlp_kernel<<<1, 256, 0, stream>>>(pools, cnt, mlp_w1, mlp_b1, mlp_w2, mlp_b2, (float*)d_out);
}

// Round 17
// 532.916 us; speedup vs baseline: 1.0488x; 1.0488x over previous
//
#include <hip/hip_runtime.h>
#include <hip/hip_bf16.h>

#define NN 50000
#define EE 800000
#define GG 16
#define IN_DIM 256
#define HID 64
#define NEG 0.2f
#define SCAN_NB 49   // ceil(50000/1024)
#define SMT 40       // nodes per matmul block (50000 = 1250*40)
#define PROJ_B (NN / SMT)   // 1250
#define ATT_B (NN / 4)      // 12500
#define EDGE_B (EE / 256)   // 3125
#define SEL_B ((NN + 255) / 256) // 196

__device__ inline float wred_sum(float v) {
    for (int o = 32; o > 0; o >>= 1) v += __shfl_xor(v, o, 64);
    return v;
}
__device__ inline float wred_max(float v) {
    for (int o = 32; o > 0; o >>= 1) v = fmaxf(v, __shfl_xor(v, o, 64));
    return v;
}
// sum float4 across the 4 slot groups (lanes differing in bits 4,5)
__device__ inline void slot_reduce4(float4& a) {
    a.x += __shfl_xor(a.x, 16, 64); a.y += __shfl_xor(a.y, 16, 64);
    a.z += __shfl_xor(a.z, 16, 64); a.w += __shfl_xor(a.w, 16, 64);
    a.x += __shfl_xor(a.x, 32, 64); a.y += __shfl_xor(a.y, 32, 64);
    a.z += __shfl_xor(a.z, 32, 64); a.w += __shfl_xor(a.w, 32, 64);
}

__device__ inline float lrelu(float a) { return a > 0.f ? a : NEG * a; }

// ---- FUSED: degree count (int atomics only) + pool-node selection ----
__global__ __launch_bounds__(256) void deg_sel_kernel(const int* __restrict__ ei,
                                                      int* __restrict__ deg,
                                                      const int* __restrict__ ntype,
                                                      int* __restrict__ nodesel,
                                                      int* __restrict__ nsel) {
    int b = blockIdx.x;
    if (b < EDGE_B) {
        int e = b * 256 + threadIdx.x;
        if (e >= EE) return;
        int d = ei[EE + e];
        atomicAdd(&deg[d], 1);
        return;
    }
    int n = (b - EDGE_B) * 256 + threadIdx.x;
    if (n >= NN) return;
    int t = ntype[n];
    if (t == 1 || t == 2) {
        int p = atomicAdd(nsel, 1);
        nodesel[p] = n;
    }
}

// ---- scan stage 1: per-block exclusive scan of deg, block totals ----
__global__ __launch_bounds__(1024) void scan1_kernel(const int* __restrict__ deg,
                                                     int* __restrict__ row_off,
                                                     int* __restrict__ bsum) {
    __shared__ int buf[1024];
    int b = blockIdx.x;
    int i = b * 1024 + threadIdx.x;
    int v = (i < NN) ? deg[i] : 0;
    buf[threadIdx.x] = v;
    __syncthreads();
    for (int ofs = 1; ofs < 1024; ofs <<= 1) {
        int t = (threadIdx.x >= ofs) ? buf[threadIdx.x - ofs] : 0;
        __syncthreads();
        buf[threadIdx.x] += t;
        __syncthreads();
    }
    if (i < NN) row_off[i] = buf[threadIdx.x] - v;   // local exclusive
    if (threadIdx.x == 1023) bsum[b] = buf[1023];
}

// ---- scan stage 2: single-wave scan of block totals ----
__global__ __launch_bounds__(64) void scan2_kernel(const int* __restrict__ bsum,
                                                   int* __restrict__ boff,
                                                   int* __restrict__ row_off) {
    int l = threadIdx.x;
    int v = (l < SCAN_NB) ? bsum[l] : 0;
    int incl = v;
    for (int ofs = 1; ofs < 64; ofs <<= 1) {
        int t = __shfl_up(incl, ofs, 64);
        if (l >= ofs) incl += t;
    }
    if (l < SCAN_NB) boff[l] = incl - v;
    if (l == 63) row_off[NN] = incl;
}

// ---- scan stage 3: apply block offsets, derive pos/inv_deg ----
__global__ __launch_bounds__(1024) void scan3_kernel(const int* __restrict__ deg,
                                                     const int* __restrict__ boff,
                                                     int* __restrict__ row_off,
                                                     int* __restrict__ pos,
                                                     float* __restrict__ inv_deg) {
    int b = blockIdx.x;
    int i = b * 1024 + threadIdx.x;
    if (i >= NN) return;
    int ro = row_off[i] + boff[b];
    row_off[i] = ro;
    pos[i] = ro;
    float idg = 1.0f / fmaxf((float)deg[i], 1.0f);
    inv_deg[i] = idg;
}

// ---- ALL weight prep in one dispatch ----
__global__ __launch_bounds__(128) void weights_kernel(const float* __restrict__ wl,
                                                      const float* __restrict__ wr,
                                                      float* __restrict__ wtp,
                                                      const float* __restrict__ w0,
                                                      const float* __restrict__ as0,
                                                      const float* __restrict__ ad0,
                                                      const float* __restrict__ we0,
                                                      const float* __restrict__ ae0,
                                                      const float* __restrict__ w1,
                                                      const float* __restrict__ as1,
                                                      const float* __restrict__ ad1,
                                                      const float* __restrict__ we1,
                                                      const float* __restrict__ ae1,
                                                      const float* __restrict__ w2,
                                                      const float* __restrict__ as2,
                                                      const float* __restrict__ ad2,
                                                      const float* __restrict__ we2,
                                                      const float* __restrict__ ae2,
                                                      float* __restrict__ wtg3,
                                                      float* __restrict__ asw3,
                                                      float* __restrict__ adw3,
                                                      float* __restrict__ wedot3) {
    int b = blockIdx.x;
    int j = threadIdx.x;     // 0..127
    if (b < 256) {
        int k = b;
        float v = (j < 64) ? wl[j * 256 + k] : wr[(j - 64) * 256 + k];
        wtp[(k >> 2) * 512 + j * 4 + (k & 3)] = v;
        return;
    }
    int L = (b - 256) >> 6;
    int k = (b - 256) & 63;
    const float* w  = (L == 0) ? w0  : (L == 1) ? w1  : w2;
    const float* as = (L == 0) ? as0 : (L == 1) ? as1 : as2;
    const float* ad = (L == 0) ? ad0 : (L == 1) ? ad1 : ad2;
    const float* we = (L == 0) ? we0 : (L == 1) ? we1 : we2;
    const float* ae = (L == 0) ? ae0 : (L == 1) ? ae1 : ae2;
    int H64 = (L == 2) ? 64 : 128;
    if (j >= H64) return;
    int h = j >> 6;
    int c = j & 63;
    float wv = w[j * 64 + k];
    wtg3[L * 8192 + (k >> 2) * (H64 * 4) + j * 4 + (k & 3)] = wv;
    float sv = wred_sum(wv * as[j]);
    float dv = wred_sum(wv * ad[j]);
    if (c == 0) {
        asw3[L * 128 + h * 64 + k] = sv;
        adw3[L * 128 + h * 64 + k] = dv;
    }
    if (k == 0) {
        float wd = wred_sum(we[j] * ae[j]);
        if (c == 0) wedot3[L * 2 + h] = wd;
    }
}

// ---- FUSED, sage-first (R10 ordering): sage_mm blocks 0..1249 (SMT=40, 20KB LDS,
//      2-stage K; fmaf chain identical to passing rounds) + CSR fill after
//      (packed int2 store: one cacheline per edge). ----
__global__ __launch_bounds__(256) void sage_fill_kernel(const float* __restrict__ x,
                                                        const float* __restrict__ wtp,
                                                        float* __restrict__ xl,
                                                        float* __restrict__ xr,
                                                        const int* __restrict__ ei,
                                                        const float* __restrict__ eattr,
                                                        int* __restrict__ pos,
                                                        int2* __restrict__ csr_pk) {
    __shared__ float xs[SMT * 128];          // 20 KB: one K-half of the 40-node tile
    if (blockIdx.x >= PROJ_B) {
        int e = (blockIdx.x - PROJ_B) * 256 + threadIdx.x;
        if (e >= EE) return;
        int d = ei[EE + e];
        int p = atomicAdd(&pos[d], 1);
        csr_pk[p] = make_int2(ei[e], __float_as_int(eattr[e]));
        return;
    }
    int node0 = blockIdx.x * SMT;
    const float4* x4 = (const float4*)(x + (size_t)node0 * 256);
    float4* xs4 = (float4*)xs;
    int jj = threadIdx.x & 63;
    int g = threadIdx.x >> 6;           // node group: 10 nodes each
    float accL[10], accR[10];
#pragma unroll
    for (int n = 0; n < 10; n++) { accL[n] = 0.f; accR[n] = 0.f; }
    for (int stage = 0; stage < 2; ++stage) {
        __syncthreads();                 // previous half's compute done before overwrite
        for (int t = threadIdx.x; t < SMT * 32; t += 256) {
            int node = t >> 5;
            int kk = t & 31;
            xs4[t] = x4[node * 64 + stage * 32 + kk];
        }
        __syncthreads();
        for (int k4i = 0; k4i < 32; k4i++) {
            int k4 = stage * 32 + k4i;
            const float4 wL = *(const float4*)&wtp[k4 * 512 + jj * 4];
            const float4 wR = *(const float4*)&wtp[k4 * 512 + (jj + 64) * 4];
#pragma unroll
            for (int n = 0; n < 10; n++) {
                const float4 xv = xs4[(g * 10 + n) * 32 + k4i];
                accL[n] = fmaf(xv.x, wL.x, accL[n]);
                accL[n] = fmaf(xv.y, wL.y, accL[n]);
                accL[n] = fmaf(xv.z, wL.z, accL[n]);
                accL[n] = fmaf(xv.w, wL.w, accL[n]);
                accR[n] = fmaf(xv.x, wR.x, accR[n]);
                accR[n] = fmaf(xv.y, wR.y, accR[n]);
                accR[n] = fmaf(xv.z, wR.z, accR[n]);
                accR[n] = fmaf(xv.w, wR.w, accR[n]);
            }
        }
    }
#pragma unroll
    for (int n = 0; n < 10; n++) {
        int node = node0 + g * 10 + n;
        xl[(size_t)node * 64 + jj] = accL[n];
        xr[(size_t)node * 64 + jj] = accR[n];
    }
}

// ---- FUSED: proj_mm<H> (blocks 0..1249) + attval (blocks 1250..) ----
template <int H>
__global__ __launch_bounds__(256) void proj_attval_kernel(const float* __restrict__ hin,
                                                          const float* __restrict__ wtgp,
                                                          float* __restrict__ hproj,
                                                          const float* __restrict__ asw,
                                                          const float* __restrict__ adw,
                                                          float* __restrict__ sval,
                                                          float* __restrict__ dval) {
    __shared__ float xs[SMT * 64];
    if (blockIdx.x < PROJ_B) {
        int node0 = blockIdx.x * SMT;
        const float4* h4 = (const float4*)(hin + (size_t)node0 * 64);
        float4* xs4 = (float4*)xs;
        for (int t = threadIdx.x; t < SMT * 16; t += 256) xs4[t] = h4[t];
        __syncthreads();
        int jj = threadIdx.x & 63;
        int g = threadIdx.x >> 6;
        float acc[H][10];
#pragma unroll
        for (int h = 0; h < H; h++)
#pragma unroll
            for (int n = 0; n < 10; n++) acc[h][n] = 0.f;
#pragma unroll 4
        for (int k4 = 0; k4 < 16; k4++) {
            float4 wv[H];
#pragma unroll
            for (int h = 0; h < H; h++)
                wv[h] = *(const float4*)&wtgp[k4 * (H * 256) + (h * 64 + jj) * 4];
#pragma unroll
            for (int n = 0; n < 10; n++) {
                const float4 xv = xs4[(g * 10 + n) * 16 + k4];
#pragma unroll
                for (int h = 0; h < H; h++) {
                    acc[h][n] = fmaf(xv.x, wv[h].x, acc[h][n]);
                    acc[h][n] = fmaf(xv.y, wv[h].y, acc[h][n]);
                    acc[h][n] = fmaf(xv.z, wv[h].z, acc[h][n]);
                    acc[h][n] = fmaf(xv.w, wv[h].w, acc[h][n]);
                }
            }
        }
#pragma unroll
        for (int h = 0; h < H; h++)
#pragma unroll
            for (int n = 0; n < 10; n++)
                hproj[(size_t)(node0 + g * 10 + n) * (H * 64) + h * 64 + jj] = acc[h][n];
        return;
    }
    // attval body (verbatim)
    int wid = ((blockIdx.x - PROJ_B) * 256 + threadIdx.x) >> 6;
    int lane = threadIdx.x & 63;
    if (wid >= NN) return;
    float hv = hin[(size_t)wid * 64 + lane];
    for (int h = 0; h < H; ++h) {
        float sv = wred_sum(hv * asw[h * 64 + lane]);
        float dv = wred_sum(hv * adw[h * 64 + lane]);
        if (lane == 0) {
            sval[wid * H + h] = sv;
            dval[wid * H + h] = dv;
        }
    }
}

// ---- SAGE aggregation + combine + relu; also computes mean_e from the CSR
//      bucket (replaces the 800K float atomics that used to build esum).
//      xl-acc fmaf chain unchanged; esum is a new independent chain. ----
__global__ __launch_bounds__(256) void sage_agg_kernel(const float* __restrict__ xl,
                                                       const float* __restrict__ xr,
                                                       const float* __restrict__ bl,
                                                       const float* __restrict__ inv_deg,
                                                       const int* __restrict__ row_off,
                                                       const int2* __restrict__ csr_pk,
                                                       float* __restrict__ hout,
                                                       float* __restrict__ mean_e) {
    int wid = blockIdx.x * 4 + (threadIdx.x >> 6);
    int lane = threadIdx.x & 63;
    if (wid >= NN) return;
    int slot = lane >> 4;
    int c4 = lane & 15;
    int r0 = row_off[wid], r1 = row_off[wid + 1];
    float4 acc = make_float4(0.f, 0.f, 0.f, 0.f);
    float es = 0.f;
    // unroll duplicates the body; fma/add chain order per lane is unchanged
#pragma unroll 4
    for (int idx = r0 + slot; idx < r1; idx += 4) {
        int2 cp = csr_pk[idx];
        int s = cp.x;
        es += __int_as_float(cp.y);
        const float4 hp = *(const float4*)&xl[(size_t)s * 64 + c4 * 4];
        acc.x += hp.x; acc.y += hp.y; acc.z += hp.z; acc.w += hp.w;
    }
    slot_reduce4(acc);
    es += __shfl_xor(es, 16, 64);   // lanes within a slot hold identical es
    es += __shfl_xor(es, 32, 64);   // -> every lane now has the bucket sum
    if (slot == 0) {
        float idg = inv_deg[wid];
        if (c4 == 0) mean_e[wid] = es * idg;
        const float4 b4 = *(const float4*)&bl[c4 * 4];
        const float4 xr4 = *(const float4*)&xr[(size_t)wid * 64 + c4 * 4];
        float4 v;
        v.x = fmaxf(acc.x * idg + b4.x + xr4.x, 0.f);
        v.y = fmaxf(acc.y * idg + b4.y + xr4.y, 0.f);
        v.z = fmaxf(acc.z * idg + b4.z + xr4.z, 0.f);
        v.w = fmaxf(acc.w * idg + b4.w + xr4.w, 0.f);
        *(float4*)&hout[(size_t)wid * 64 + c4 * 4] = v;
    }
}

// ---- GAT: frozen FP bodies (round-5 expressions verbatim); packed int2 loads. ----
__global__ __launch_bounds__(256) void gat_kernel(const float* __restrict__ hproj,
                                                  const float* __restrict__ sval,
                                                  const float* __restrict__ dval,
                                                  const float* __restrict__ wedot_buf,
                                                  const float* __restrict__ bias,
                                                  const float* __restrict__ mean_e,
                                                  const int* __restrict__ row_off,
                                                  const int2* __restrict__ csr_pk,
                                                  float* __restrict__ hout, int H,
                                                  const int* __restrict__ nodesel,
                                                  const int* __restrict__ nsel) {
    int wid = blockIdx.x * 4 + (threadIdx.x >> 6);
    int lane = threadIdx.x & 63;
    if (nodesel) {
        if (wid >= *nsel) return;
        wid = nodesel[wid];
    }
    if (wid >= NN) return;
    int slot = lane >> 4;
    int c4 = lane & 15;
    int H64 = H * 64;
    int r0 = row_off[wid], r1 = row_off[wid + 1];
    float me = mean_e[wid];
    float4 acc = make_float4(0.f, 0.f, 0.f, 0.f);
    for (int h = 0; h < H; ++h) {
        float wedot = wedot_buf[h];
        float dv = dval[wid * H + h];
        float a_self = lrelu(sval[wid * H + h] + dv + me * wedot);
        // single pass: online max + denom, lane-strided
        float m_l = -INFINITY, den_l = 0.f;
        for (int idx = r0 + lane; idx < r1; idx += 64) {
            int2 cp = csr_pk[idx];
            int s = cp.x;
            float a = lrelu(sval[s * H + h] + dv + __int_as_float(cp.y) * wedot);
            float mn = fmaxf(m_l, a);
            den_l = den_l * __expf(m_l - mn) + __expf(a - mn);
            m_l = mn;
        }
        float m = fmaxf(wred_max(m_l), a_self);
        float den = wred_sum(den_l * __expf(m_l - m)) + __expf(a_self - m);
        float inv_den = 1.0f / den;
        // weighted gather: 4 edges in flight (one per slot), float4 per lane
        for (int idx = r0 + slot; idx < r1; idx += 4) {
            int2 cp = csr_pk[idx];
            int s = cp.x;
            float a = lrelu(sval[s * H + h] + dv + __int_as_float(cp.y) * wedot);
            float c = __expf(a - m) * inv_den;
            const float4 hp = *(const float4*)&hproj[(size_t)s * H64 + h * 64 + c4 * 4];
            acc.x = fmaf(c, hp.x, acc.x);
            acc.y = fmaf(c, hp.y, acc.y);
            acc.z = fmaf(c, hp.z, acc.z);
            acc.w = fmaf(c, hp.w, acc.w);
        }
        if (slot == 0) {  // self-loop contribution
            float c = __expf(a_self - m) * inv_den;
            const float4 hp = *(const float4*)&hproj[(size_t)wid * H64 + h * 64 + c4 * 4];
            acc.x = fmaf(c, hp.x, acc.x);
            acc.y = fmaf(c, hp.y, acc.y);
            acc.z = fmaf(c, hp.z, acc.z);
            acc.w = fmaf(c, hp.w, acc.w);
        }
    }
    slot_reduce4(acc);
    if (slot == 0) {
        float invH = 1.0f / (float)H;
        const float4 b4 = *(const float4*)&bias[c4 * 4];
        float4 v;
        v.x = fmaxf(acc.x * invH + b4.x, 0.f);
        v.y = fmaxf(acc.y * invH + b4.y, 0.f);
        v.z = fmaxf(acc.z * invH + b4.z, 0.f);
        v.w = fmaxf(acc.w * invH + b4.w, 0.f);
        *(float4*)&hout[(size_t)wid * 64 + c4 * 4] = v;
    }
}

// ---- masked mean pool: batch sorted -> register accumulate, flush on boundary ----
__global__ __launch_bounds__(256) void pool_kernel(const float* __restrict__ h,
                                                   const int* __restrict__ ntype,
                                                   const int* __restrict__ batch,
                                                   float* __restrict__ pool,
                                                   float* __restrict__ cnt) {
    int nwaves = gridDim.x * 4;
    int wid = blockIdx.x * 4 + (threadIdx.x >> 6);
    int lane = threadIdx.x & 63;
    int chunk = (NN + nwaves - 1) / nwaves;
    int n0 = wid * chunk;
    int n1 = min(n0 + chunk, NN);
    if (n0 >= NN) return;
    float acc1 = 0.f, acc2 = 0.f;
    int c1 = 0, c2 = 0;
    int cur_g = batch[n0];
    for (int n = n0; n < n1; ++n) {
        int g = batch[n];
        if (g != cur_g) {
            if (c1) {
                atomicAdd(&pool[(0 * GG + cur_g) * 64 + lane], acc1);
                if (lane == 0) atomicAdd(&cnt[0 * GG + cur_g], (float)c1);
            }
            if (c2) {
                atomicAdd(&pool[(1 * GG + cur_g) * 64 + lane], acc2);
                if (lane == 0) atomicAdd(&cnt[1 * GG + cur_g], (float)c2);
            }
            acc1 = acc2 = 0.f;
            c1 = c2 = 0;
            cur_g = g;
        }
        int t = ntype[n];
        if (t == 1) { acc1 += h[n * 64 + lane]; c1++; }
        else if (t == 2) { acc2 += h[n * 64 + lane]; c2++; }
    }
    if (c1) {
        atomicAdd(&pool[(0 * GG + cur_g) * 64 + lane], acc1);
        if (lane == 0) atomicAdd(&cnt[0 * GG + cur_g], (float)c1);
    }
    if (c2) {
        atomicAdd(&pool[(1 * GG + cur_g) * 64 + lane], acc2);
        if (lane == 0) atomicAdd(&cnt[1 * GG + cur_g], (float)c2);
    }
}

// ---- final MLP ----
__global__ __launch_bounds__(256) void mlp_kernel(const float* __restrict__ pool,
                                                  const float* __restrict__ cnt,
                                                  const float* __restrict__ w1,
                                                  const float* __restrict__ b1,
                                                  const float* __restrict__ w2,
                                                  const float* __restrict__ b2,
                                                  float* __restrict__ out) {
    __shared__ float ro[GG * 128];
    __shared__ float hid[GG * 64];
    int tid = threadIdx.x;
    for (int t = tid; t < GG * 128; t += 256) {
        int g = t >> 7;
        int j = t & 127;
        int part = j >> 6;
        float c = fmaxf(cnt[part * GG + g], 1.0f);
        ro[t] = pool[(part * GG + g) * 64 + (j & 63)] / c;
    }
    __syncthreads();
    for (int t = tid; t < GG * 64; t += 256) {
        int g = t >> 6;
        int i = t & 63;
        float s = b1[i];
        for (int j = 0; j < 128; j++) s = fmaf(ro[g * 128 + j], w1[i * 128 + j], s);
        hid[t] = fmaxf(s, 0.f);
    }
    __syncthreads();
    if (tid < GG) {
        float s = b2[0];
        for (int i = 0; i < 64; i++) s = fmaf(hid[tid * 64 + i], w2[i], s);
        out[tid] = s;
    }
}

extern "C" void kernel_launch(void* const* d_in, const int* in_sizes, int n_in,
                              void* d_out, int out_size, void* d_ws, size_t ws_size,
                              hipStream_t stream) {
    const float* x       = (const float*)d_in[0];
    const int*   ei      = (const int*)d_in[1];
    const int*   ntype   = (const int*)d_in[2];
    const float* eattr   = (const float*)d_in[3];
    const int*   batch   = (const int*)d_in[4];
    const float* sage_wl = (const float*)d_in[5];
    const float* sage_bl = (const float*)d_in[6];
    const float* sage_wr = (const float*)d_in[7];
    const float* mlp_w1  = (const float*)d_in[8];
    const float* mlp_b1  = (const float*)d_in[9];
    const float* mlp_w2  = (const float*)d_in[10];
    const float* mlp_b2  = (const float*)d_in[11];
    const float* gw[3]  = {(const float*)d_in[12], (const float*)d_in[18], (const float*)d_in[24]};
    const float* gas[3] = {(const float*)d_in[13], (const float*)d_in[19], (const float*)d_in[25]};
    const float* gad[3] = {(const float*)d_in[14], (const float*)d_in[20], (const float*)d_in[26]};
    const float* gwe[3] = {(const float*)d_in[15], (const float*)d_in[21], (const float*)d_in[27]};
    const float* gae[3] = {(const float*)d_in[16], (const float*)d_in[22], (const float*)d_in[28]};
    const float* gb[3]  = {(const float*)d_in[17], (const float*)d_in[23], (const float*)d_in[29]};

    char* base = (char*)d_ws;
    size_t o = 0;
    auto alloc = [&](size_t bytes) -> char* {
        char* p = base + o;
        o = (o + bytes + 255) & ~(size_t)255;
        return p;
    };
    // deg + nsel contiguous -> single memset
    char*  zblock1 = alloc(((size_t)NN + 1) * 4);
    int*   deg     = (int*)zblock1;
    int*   nsel    = (int*)(zblock1 + (size_t)NN * 4);
    float* mean_e  = (float*)alloc(NN * 4);
    float* inv_deg = (float*)alloc(NN * 4);
    int*   row_off = (int*)  alloc((NN + 1) * 4);
    int*   pos     = (int*)  alloc(NN * 4);
    int*   bsum    = (int*)  alloc(64 * 4);
    int*   boff    = (int*)  alloc(64 * 4);
    int*   nodesel = (int*)  alloc(NN * 4);
    int2*  csr_pk  = (int2*) alloc((size_t)EE * 8);
    float* xl      = (float*)alloc((size_t)NN * 64 * 4);
    float* xr      = (float*)alloc((size_t)NN * 64 * 4);
    float* hA      = (float*)alloc((size_t)NN * 64 * 4);
    float* hB      = (float*)alloc((size_t)NN * 64 * 4);
    float* hproj   = (float*)alloc((size_t)NN * 128 * 4);
    float* sval    = (float*)alloc((size_t)NN * 2 * 4);
    float* dval    = (float*)alloc((size_t)NN * 2 * 4);
    float* wt      = (float*)alloc(256 * 128 * 4);
    float* wtg3    = (float*)alloc(3 * 8192 * 4);
    float* asw3    = (float*)alloc(3 * 128 * 4);
    float* adw3    = (float*)alloc(3 * 128 * 4);
    float* wedot3  = (float*)alloc(3 * 2 * 4);
    // pools + cnt contiguous -> single memset
    char*  zblock2 = alloc((2 * GG * 64 + 2 * GG) * 4);
    float* pools   = (float*)zblock2;
    float* cnt     = (float*)(zblock2 + 2 * GG * 64 * 4);

    hipMemsetAsync(zblock1, 0, ((size_t)NN + 1) * 4, stream);
    hipMemsetAsync(zblock2, 0, (2 * GG * 64 + 2 * GG) * 4, stream);

    weights_kernel<<<448, 128, 0, stream>>>(sage_wl, sage_wr, wt,
                                            gw[0], gas[0], gad[0], gwe[0], gae[0],
                                            gw[1], gas[1], gad[1], gwe[1], gae[1],
                                            gw[2], gas[2], gad[2], gwe[2], gae[2],
                                            wtg3, asw3, adw3, wedot3);
    deg_sel_kernel<<<EDGE_B + SEL_B, 256, 0, stream>>>(ei, deg, ntype, nodesel, nsel);
    scan1_kernel<<<SCAN_NB, 1024, 0, stream>>>(deg, row_off, bsum);
    scan2_kernel<<<1, 64, 0, stream>>>(bsum, boff, row_off);
    scan3_kernel<<<SCAN_NB, 1024, 0, stream>>>(deg, boff, row_off, pos, inv_deg);

    // fused, sage-first: sage projection (20KB LDS, 2-stage K) || CSR fill (packed int2)
    sage_fill_kernel<<<PROJ_B + EDGE_B, 256, 0, stream>>>(x, wt, xl, xr,
                                                          ei, eattr, pos, csr_pk);
    sage_agg_kernel<<<NN / 4, 256, 0, stream>>>(xl, xr, sage_bl, inv_deg, row_off,
                                                csr_pk, hA, mean_e);

    float* hin = hA;
    float* hout = hB;
    for (int L = 0; L < 3; ++L) {
        int H = (L == 2) ? 1 : 2;
        const float* wtgL = wtg3 + (size_t)L * 8192;
        const float* aswL = asw3 + L * 128;
        const float* adwL = adw3 + L * 128;
        const float* wedL = wedot3 + L * 2;
        if (H == 2)
            proj_attval_kernel<2><<<PROJ_B + ATT_B, 256, 0, stream>>>(hin, wtgL, hproj,
                                                                     aswL, adwL, sval, dval);
        else
            proj_attval_kernel<1><<<PROJ_B + ATT_B, 256, 0, stream>>>(hin, wtgL, hproj,
                                                                     aswL, adwL, sval, dval);
        gat_kernel<<<NN / 4, 256, 0, stream>>>(hproj, sval, dval, wedL, gb[L],
                                               mean_e, row_off, csr_pk, hout, H,
                                               (L == 2) ? nodesel : nullptr,
                                               (L == 2) ? nsel : nullptr);
        float* tmp = hin; hin = hout; hout = tmp;
    }
    // final features now in hin
    pool_kernel<<<512, 256, 0, stream>>>(hin, ntype, batch, pools, cnt);
    mlp_kernel<<<1, 256, 0, stream>>>(pools, cnt, mlp_w1, mlp_b1, mlp_w2, mlp_b2, (float*)d_out);
}